// Round 1
// baseline (83.933 us; speedup 1.0000x reference)
//
#include <hip/hip_runtime.h>

// Problem constants (from reference):
#define BB 8
#define NN 32768
#define CC 4
#define MM 11          // memory length (FIR taps)
#define KK 55          // D*M
#define THREADS 256
#define SAMP 128                   // output samples per block
#define HALO (MM - 1)              // 10
#define SS2 (SAMP + HALO)          // 138 staged time samples
#define NF4 (2 * SS2)              // 276 staged float4 (pair-interleaved, mirrors global)

// out[b,c,n] = sum_{j=0..10} z[n-10+j] * ( sum_d W[c, d*11+j] * |z[n-10+j]|^d )
// z[t] = x[b,t,c,0] + i x[b,t,c,1], zero for t<0.
//
// Round-4 design: pair-select moved from blockIdx.z into (tid & 1).
// Each 256-thread block covers 128 samples x BOTH channel pairs:
//   thread tid -> sample s = tid>>1, pair p = tid&1 (channels 2p, 2p+1).
// This keeps full residency (2048 blocks = 8 blocks/CU, 32 waves/CU) AND makes
// every global access fully dense:
//   - staging: staged float4 idx == global float4 idx (g0 + idx), 16B/lane coalesced
//   - LDS:     zs[tid + 2j] = dense b128; as2[tid + 2j] = dense b64 (conflict-free)
//   - store:   out float4 idx = base + tid, full-line coalesced
// The only tax: weight row depends on tid&1 -> uniform scalar loads for both
// candidate rows + v_cndmask select (110 cndmask/thread, VALU-side, cheap vs
// pushing 440 weight floats through the contended LDS pipe).

__device__ __forceinline__ float wsel(const float* __restrict__ Wrow, bool hi, int o) {
    // Wrow points at row c (c in {0,1}); candidate rows are c and c+2.
    // Both loads are wave-uniform -> s_load; select is one v_cndmask.
    float lo = Wrow[o];
    float hv = Wrow[2 * KK + o];
    return hi ? hv : lo;
}

__global__ __launch_bounds__(THREADS, 8)
void gmp_kernel(const float* __restrict__ x,
                const float* __restrict__ W,
                float* __restrict__ out) {
    __shared__ float4 zs[NF4];    // (re, im, re, im) of one channel pair per slot
    __shared__ float2 as2[NF4];   // |z| for the two channels of that slot's pair

    const int tid = threadIdx.x;
    const int b  = blockIdx.y;
    const int n0 = blockIdx.x * SAMP;

    const float4* xg = (const float4*)x + (size_t)b * NN * 2;
    const int g0 = (n0 - HALO) * 2;   // first staged global float4 index (may be <0)

    // Stage 276 float4s = times n0-10 .. n0+127 for both pairs, exactly in
    // global order -> dense coalesced loads, dense b128/b64 LDS writes.
    for (int idx = tid; idx < NF4; idx += THREADS) {
        float4 v = make_float4(0.f, 0.f, 0.f, 0.f);
        if (g0 + idx >= 0) v = xg[g0 + idx];   // t<0 -> zero (left pad)
        zs[idx] = v;
        as2[idx] = make_float2(sqrtf(fmaf(v.x, v.x, v.y * v.y)),
                               sqrtf(fmaf(v.z, v.z, v.w * v.w)));
    }
    __syncthreads();

    const bool hi = (tid & 1);        // pair select: channels {0,1} vs {2,3}

    float ar0 = 0.f, ai0 = 0.f, ar1 = 0.f, ai1 = 0.f;

    #pragma unroll
    for (int j = 0; j < MM; j++) {
        // staged slot for (sample s + j, pair p): 2*(s+j)+p = tid + 2j
        const float4 v = zs[tid + 2 * j];
        const float2 a = as2[tid + 2 * j];
        // channel 2p (rows 0 or 2)
        {
            float pw = wsel(W, hi, 4 * MM + j);
            pw = fmaf(pw, a.x, wsel(W, hi, 3 * MM + j));
            pw = fmaf(pw, a.x, wsel(W, hi, 2 * MM + j));
            pw = fmaf(pw, a.x, wsel(W, hi, 1 * MM + j));
            pw = fmaf(pw, a.x, wsel(W, hi, 0 * MM + j));
            ar0 = fmaf(v.x, pw, ar0);
            ai0 = fmaf(v.y, pw, ai0);
        }
        // channel 2p+1 (rows 1 or 3)
        {
            const float* W1 = W + KK;
            float pw = wsel(W1, hi, 4 * MM + j);
            pw = fmaf(pw, a.y, wsel(W1, hi, 3 * MM + j));
            pw = fmaf(pw, a.y, wsel(W1, hi, 2 * MM + j));
            pw = fmaf(pw, a.y, wsel(W1, hi, 1 * MM + j));
            pw = fmaf(pw, a.y, wsel(W1, hi, 0 * MM + j));
            ar1 = fmaf(v.z, pw, ar1);
            ai1 = fmaf(v.w, pw, ai1);
        }
    }

    // out float4 index = (b*NN + n0 + s)*2 + p = base + tid -> fully dense store.
    float4* og = (float4*)out + ((size_t)(b * NN + n0) * 2 + tid);
    *og = make_float4(ar0, ai0, ar1, ai1);
}

extern "C" void kernel_launch(void* const* d_in, const int* in_sizes, int n_in,
                              void* d_out, int out_size, void* d_ws, size_t ws_size,
                              hipStream_t stream) {
    const float* x = (const float*)d_in[0];   // [B,N,C,2] fp32
    const float* W = (const float*)d_in[1];   // [C,K] fp32
    float* out = (float*)d_out;               // [B,N,C,2] fp32

    dim3 grid(NN / SAMP, BB, 1);              // 256 x 8 = 2048 blocks
    gmp_kernel<<<grid, THREADS, 0, stream>>>(x, W, out);
}

// Round 2
// 64.441 us; speedup vs baseline: 1.3025x; 1.3025x over previous
//
#include <hip/hip_runtime.h>

// Problem constants (from reference):
#define BB 8
#define NN 32768
#define CC 4
#define MM 11          // memory length (FIR taps)
#define KK 55          // D*M
#define THREADS 256
#define SAMP 128                   // output samples per block
#define HALO (MM - 1)              // 10
#define SS2 (SAMP + HALO)          // 138 staged time samples
#define NF4 (2 * SS2)              // 276 staged float4 (pair-interleaved in global)

// out[b,c,n] = sum_{j=0..10} z[n-10+j] * ( sum_d W[c, d*11+j] * |z[n-10+j]|^d )
// z[t] = x[b,t,c,0] + i x[b,t,c,1], zero for t<0.
//
// Round-5 design: pair select is WAVE-uniform (p = wave_id & 1), not lane-
// divergent (round-4's tid&1 demoted all 110 weight reads to per-lane VMEM —
// 2x regression). Block = 256 threads = 4 waves:
//   wave w, lane l:  pair p = w&1 (channels 2p,2p+1), sample s = l + 64*(w>>1).
// Wins kept from the dense layout:
//   - staging: global float4 idx = g0 + tid, fully dense 16B/lane -> x fetched
//     ONCE per block (round 3 fetched every line twice at 32B stride).
//   - stores: waves p=0 / p=1 of the SAME block write complementary 32B-stride
//     halves of the same lines -> merged in the local L2 (round-3's partner
//     block was 1024 dispatches away, likely another XCD).
//   - weights: p is SGPR -> W rows are uniform pointers -> s_load (scalar
//     cache), zero divergent operands.
//   - LDS de-interleaved per pair: compute reads are canonical dense
//     b128 (16B lane stride) / b64 (8B) -> conflict-free.
// Residency: 2048 blocks x 4 waves = 32 waves/CU (full).

__global__ __launch_bounds__(THREADS, 8)
void gmp_kernel(const float* __restrict__ x,
                const float* __restrict__ W,
                float* __restrict__ out) {
    __shared__ float4 zs[2][SS2];    // [pair][time]: (re_c, im_c, re_c+1, im_c+1)
    __shared__ float2 as2[2][SS2];   // [pair][time]: |z| of the pair's channels

    const int tid = threadIdx.x;
    const int b  = blockIdx.y;
    const int n0 = blockIdx.x * SAMP;

    const float4* xg = (const float4*)x + (size_t)b * NN * 2;
    const int g0 = (n0 - HALO) * 2;   // first staged global float4 index (may be <0)

    // Stage 276 float4s = times n0-10 .. n0+127, both pairs, in global order.
    for (int idx = tid; idx < NF4; idx += THREADS) {
        float4 v = make_float4(0.f, 0.f, 0.f, 0.f);
        if (g0 + idx >= 0) v = xg[g0 + idx];   // t<0 -> zero (left pad)
        const int pr = idx & 1;                // pair of this float4
        const int ts = idx >> 1;               // time slot
        zs[pr][ts] = v;
        as2[pr][ts] = make_float2(sqrtf(fmaf(v.x, v.x, v.y * v.y)),
                                  sqrtf(fmaf(v.z, v.z, v.w * v.w)));
    }
    __syncthreads();

    // Wave-uniform pair select (readfirstlane forces SGPR -> scalar weight path).
    const int w = __builtin_amdgcn_readfirstlane(tid >> 6);
    const int p = w & 1;                       // channels 2p, 2p+1
    const int s = (tid & 63) + ((w >> 1) << 6);  // sample within block: 0..127

    const float* W0 = W + (2 * p) * KK;        // uniform -> s_load
    const float* W1 = W + (2 * p + 1) * KK;

    float ar0 = 0.f, ai0 = 0.f, ar1 = 0.f, ai1 = 0.f;

    #pragma unroll
    for (int j = 0; j < MM; j++) {
        const float4 v = zs[p][s + j];
        const float2 a = as2[p][s + j];
        // channel 2p
        {
            float pw = W0[4 * MM + j];
            pw = fmaf(pw, a.x, W0[3 * MM + j]);
            pw = fmaf(pw, a.x, W0[2 * MM + j]);
            pw = fmaf(pw, a.x, W0[1 * MM + j]);
            pw = fmaf(pw, a.x, W0[0 * MM + j]);
            ar0 = fmaf(v.x, pw, ar0);
            ai0 = fmaf(v.y, pw, ai0);
        }
        // channel 2p+1
        {
            float pw = W1[4 * MM + j];
            pw = fmaf(pw, a.y, W1[3 * MM + j]);
            pw = fmaf(pw, a.y, W1[2 * MM + j]);
            pw = fmaf(pw, a.y, W1[1 * MM + j]);
            pw = fmaf(pw, a.y, W1[0 * MM + j]);
            ar1 = fmaf(v.z, pw, ar1);
            ai1 = fmaf(v.w, pw, ai1);
        }
    }

    // out float4 index = (b*NN + n0 + s)*2 + p; waves p=0/p=1 interleave to
    // cover full lines within the block.
    const int n = n0 + s;
    float4* og = (float4*)out + ((size_t)(b * NN + n) * 2 + p);
    *og = make_float4(ar0, ai0, ar1, ai1);
}

extern "C" void kernel_launch(void* const* d_in, const int* in_sizes, int n_in,
                              void* d_out, int out_size, void* d_ws, size_t ws_size,
                              hipStream_t stream) {
    const float* x = (const float*)d_in[0];   // [B,N,C,2] fp32
    const float* W = (const float*)d_in[1];   // [C,K] fp32
    float* out = (float*)d_out;               // [B,N,C,2] fp32

    dim3 grid(NN / SAMP, BB, 1);              // 256 x 8 = 2048 blocks
    gmp_kernel<<<grid, THREADS, 0, stream>>>(x, W, out);
}